// Round 8
// baseline (746.581 us; speedup 1.0000x reference)
//
#include <hip/hip_runtime.h>
#include <stdint.h>

#define NN    6000
#define KNNC  10
#define MM    (NN * 2 * (KNNC + 1))   // 132000
#define DD    (2 * NN)                // 12000
#define LCH   3                       // hidden layers (LC-1)
#define BLK   256

#define NV          ((long long)DD * DD / 4)   // 36,000,000 float4s
#define FILL_BLOCKS 4096
#define MLP_BLOCKS  ((MM + BLK - 1) / BLK)     // 516

// ---------------- kernel 1: pure zero-fill, 8 VGPR, max occupancy ----------
__global__ __launch_bounds__(BLK) void fill_out(float* __restrict__ out) {
    float4 z = make_float4(0.f, 0.f, 0.f, 0.f);
    float4* outv = (float4*)out;
    long long i = (long long)blockIdx.x * BLK + threadIdx.x;
    const long long stride = (long long)FILL_BLOCKS * BLK;
    for (; i < NV; i += stride) outv[i] = z;
}

// ---------------- kernel 2: pure MLP, one row per thread -------------------
__global__ __launch_bounds__(BLK) void mlp(
    const float* __restrict__ CK,    // [MM,3]
    const float* __restrict__ Win,   // [3,64]
    const float* __restrict__ bin,   // [64]
    const float* __restrict__ Whid,  // [3,64,64]
    const float* __restrict__ bhid,  // [3,64]
    const float* __restrict__ Wout,  // [64,4]
    const float* __restrict__ bout,  // [4]
    float* __restrict__ vals)        // [MM,2] (workspace)
{
    const int m = blockIdx.x * BLK + threadIdx.x;
    if (m >= MM) return;

    const float x0 = CK[m * 3 + 0];
    const float x1 = CK[m * 3 + 1];
    const float x2 = CK[m * 3 + 2];

    // Input layer 3 -> 64; weight/bias reads wave-uniform (broadcast).
    float h[64];
#pragma unroll
    for (int j = 0; j < 64; j++) {
        float a = bin[j];
        a = fmaf(x0, Win[j],       a);
        a = fmaf(x1, Win[64 + j],  a);
        a = fmaf(x2, Win[128 + j], a);
        h[j] = fmaxf(a, 0.0f);
    }

    // Hidden layers: g_j = sum_k W[k][j] * h_k (row-major W matches h @ W).
#pragma unroll 1
    for (int l = 0; l < LCH; l++) {
        const float4* __restrict__ W4 = (const float4*)(Whid + (l << 12));
        const float*  __restrict__ bh = bhid + (l << 6);
        float g[64];
#pragma unroll
        for (int j = 0; j < 64; j++) g[j] = bh[j];
#pragma unroll 2
        for (int k = 0; k < 64; k++) {
            const float hk = h[k];
            const float4* __restrict__ Wk = W4 + (k << 4);   // row k: 16 float4s
#pragma unroll
            for (int j4 = 0; j4 < 16; j4++) {
                float4 w = Wk[j4];
                g[j4 * 4 + 0] = fmaf(w.x, hk, g[j4 * 4 + 0]);
                g[j4 * 4 + 1] = fmaf(w.y, hk, g[j4 * 4 + 1]);
                g[j4 * 4 + 2] = fmaf(w.z, hk, g[j4 * 4 + 2]);
                g[j4 * 4 + 3] = fmaf(w.w, hk, g[j4 * 4 + 3]);
            }
        }
#pragma unroll
        for (int j = 0; j < 64; j++) h[j] = fmaxf(g[j], 0.0f);
    }

    // Output layer collapsed over mi: vals[:,mj] = C[:,mj] + C[:,mj+2]
    float v0 = bout[0] + bout[2];
    float v1 = bout[1] + bout[3];
#pragma unroll
    for (int k = 0; k < 64; k++) {
        float4 wo = *((const float4*)Wout + k);
        v0 = fmaf(h[k], wo.x + wo.z, v0);
        v1 = fmaf(h[k], wo.y + wo.w, v1);
    }
    vals[m * 2 + 0] = v0;
    vals[m * 2 + 1] = v1;
}

// ---------------- kernel 3: scatter-add --------------------------------------
__global__ __launch_bounds__(BLK) void scatter_add(
    const float* __restrict__ vals,   // [MM,2]
    const int* __restrict__ coo,      // [2,MM]
    float* __restrict__ out)          // [DD*DD]
{
    const int t = blockIdx.x * BLK + threadIdx.x;
    if (t >= MM) return;
    const int r2 = coo[t] * 2;        // row index * MODES
    const int c2 = coo[MM + t] * 2;   // col index * MODES
    const float v0 = vals[t * 2 + 0];
    const float v1 = vals[t * 2 + 1];
    // mj=0: element (r2, c2); mj=1: element (r2+1, c2+1) = +DD+1 flat
    const long long f0 = (long long)r2 * DD + c2;
    atomicAdd(out + f0, v0);
    atomicAdd(out + f0 + DD + 1, v1);
}

extern "C" void kernel_launch(void* const* d_in, const int* in_sizes, int n_in,
                              void* d_out, int out_size, void* d_ws, size_t ws_size,
                              hipStream_t stream) {
    const float* CK   = (const float*)d_in[0];
    const float* Win  = (const float*)d_in[1];
    const float* bin  = (const float*)d_in[2];
    const float* Whid = (const float*)d_in[3];
    const float* bhid = (const float*)d_in[4];
    const float* Wout = (const float*)d_in[5];
    const float* bout = (const float*)d_in[6];
    const int* coo    = (const int*)d_in[7];
    float* out        = (float*)d_out;
    float* vals       = (float*)d_ws;

    fill_out<<<FILL_BLOCKS, BLK, 0, stream>>>(out);
    mlp<<<MLP_BLOCKS, BLK, 0, stream>>>(CK, Win, bin, Whid, bhid, Wout, bout, vals);
    scatter_add<<<MLP_BLOCKS, BLK, 0, stream>>>(vals, coo, out);
}

// Round 9
// 736.844 us; speedup vs baseline: 1.0132x; 1.0132x over previous
//
#include <hip/hip_runtime.h>
#include <stdint.h>

#define NN    6000
#define KNNC  10
#define MM    (NN * 2 * (KNNC + 1))   // 132000
#define DD    (2 * NN)                // 12000
#define BLK   256

#define NV          ((long long)DD * DD / 4)   // 36,000,000 float4s
#define FILL_BLOCKS 4096
#define MLP_BLOCKS  512                         // 2048 waves
#define NWAVES      (MLP_BLOCKS * 4)
#define NGRP        ((MM + 3) / 4)              // 33000 groups of 4 rows

// ---------------- kernel 1: pure zero-fill, 8 VGPR, max occupancy ----------
__global__ __launch_bounds__(BLK) void fill_out(float* __restrict__ out) {
    float4 z = make_float4(0.f, 0.f, 0.f, 0.f);
    float4* outv = (float4*)out;
    long long i = (long long)blockIdx.x * BLK + threadIdx.x;
    const long long stride = (long long)FILL_BLOCKS * BLK;
    for (; i < NV; i += stride) outv[i] = z;
}

// lane-broadcast: VALU readlane -> SGPR (no LDS/VMEM pipe involvement)
__device__ __forceinline__ float rlane(float v, int l) {
    return __builtin_bit_cast(float,
        __builtin_amdgcn_readlane(__builtin_bit_cast(int, v), l));
}

// ---------------- kernel 2: MLP + scatter, one row per wave ----------------
// lane = neuron index j. Lane j holds weight columns W_l[k][j] (k=0..63,
// l=0..2) in 192 VGPRs, loaded once (coalesced). Inner loop: readlane h_k
// (VALU) + fma with SGPR operand -> zero memory ops per FMA. 4 rows in
// flight per wave for ILP. Output layer: per-lane partials, shfl_xor
// butterfly reduce (LDS pipe, hides under VALU), then fused atomics.
__global__ __launch_bounds__(BLK, 2) void mlp_scatter(
    const float* __restrict__ CK,    // [MM,3]
    const float* __restrict__ Win,   // [3,64]
    const float* __restrict__ bin,   // [64]
    const float* __restrict__ Whid,  // [3,64,64]
    const float* __restrict__ bhid,  // [3,64]
    const float* __restrict__ Wout,  // [64,4]
    const float* __restrict__ bout,  // [4]
    const int*   __restrict__ coo,   // [2,MM]
    float* __restrict__ out)         // [DD*DD], already zeroed (stream order)
{
    const int tid  = threadIdx.x;
    const int lane = tid & 63;
    const int gwid = blockIdx.x * 4 + (tid >> 6);   // global wave id

    // ---- one-time register-resident weight load (coalesced per k) ----
    float W0[64], W1[64], W2[64];
#pragma unroll
    for (int k = 0; k < 64; k++) W0[k] = Whid[k * 64 + lane];
#pragma unroll
    for (int k = 0; k < 64; k++) W1[k] = Whid[4096 + k * 64 + lane];
#pragma unroll
    for (int k = 0; k < 64; k++) W2[k] = Whid[8192 + k * 64 + lane];

    const float wi0 = Win[lane], wi1 = Win[64 + lane], wi2 = Win[128 + lane];
    const float b0  = bin[lane];
    const float bh0 = bhid[lane], bh1 = bhid[64 + lane], bh2 = bhid[128 + lane];
    const float4 wo = ((const float4*)Wout)[lane];
    const float wc0 = wo.x + wo.z;                  // collapsed over mi
    const float wc1 = wo.y + wo.w;
    const float bo0 = bout[0] + bout[2];
    const float bo1 = bout[1] + bout[3];

#define HIDDEN(W, BH)                                                   \
    {                                                                   \
        float g0 = (BH), g1 = (BH), g2 = (BH), g3 = (BH);               \
        _Pragma("unroll")                                               \
        for (int k = 0; k < 64; k++) {                                  \
            g0 = fmaf(W[k], rlane(h0, k), g0);                          \
            g1 = fmaf(W[k], rlane(h1, k), g1);                          \
            g2 = fmaf(W[k], rlane(h2, k), g2);                          \
            g3 = fmaf(W[k], rlane(h3, k), g3);                          \
        }                                                               \
        h0 = fmaxf(g0, 0.f); h1 = fmaxf(g1, 0.f);                       \
        h2 = fmaxf(g2, 0.f); h3 = fmaxf(g3, 0.f);                       \
    }

    for (int grp = gwid; grp < NGRP; grp += NWAVES) {
        const int rowbase = grp * 4;

        // cooperative CK load for 4 rows (12 floats) in one coalesced read
        float vck = 0.f;
        const int cidx = rowbase * 3 + lane;
        if (lane < 12 && cidx < MM * 3) vck = CK[cidx];

        // ---- input layer 3 -> 64 (lane j computes neuron j) ----
        float h0 = fmaxf(fmaf(rlane(vck, 2), wi2,
                         fmaf(rlane(vck, 1), wi1,
                         fmaf(rlane(vck, 0), wi0, b0))), 0.f);
        float h1 = fmaxf(fmaf(rlane(vck, 5), wi2,
                         fmaf(rlane(vck, 4), wi1,
                         fmaf(rlane(vck, 3), wi0, b0))), 0.f);
        float h2 = fmaxf(fmaf(rlane(vck, 8), wi2,
                         fmaf(rlane(vck, 7), wi1,
                         fmaf(rlane(vck, 6), wi0, b0))), 0.f);
        float h3 = fmaxf(fmaf(rlane(vck, 11), wi2,
                         fmaf(rlane(vck, 10), wi1,
                         fmaf(rlane(vck, 9), wi0, b0))), 0.f);

        // ---- hidden layers (zero memory ops) ----
        HIDDEN(W0, bh0)
        HIDDEN(W1, bh1)
        HIDDEN(W2, bh2)

        // ---- output layer: per-lane partials, butterfly reduce ----
        float p00 = h0 * wc0, p01 = h0 * wc1;
        float p10 = h1 * wc0, p11 = h1 * wc1;
        float p20 = h2 * wc0, p21 = h2 * wc1;
        float p30 = h3 * wc0, p31 = h3 * wc1;
#pragma unroll
        for (int m = 32; m; m >>= 1) {
            p00 += __shfl_xor(p00, m, 64);  p01 += __shfl_xor(p01, m, 64);
            p10 += __shfl_xor(p10, m, 64);  p11 += __shfl_xor(p11, m, 64);
            p20 += __shfl_xor(p20, m, 64);  p21 += __shfl_xor(p21, m, 64);
            p30 += __shfl_xor(p30, m, 64);  p31 += __shfl_xor(p31, m, 64);
        }

        // lane r (r<4) takes row rowbase+r and issues the two atomics
        float a0 = lane == 0 ? p00 : lane == 1 ? p10 : lane == 2 ? p20 : p30;
        float a1 = lane == 0 ? p01 : lane == 1 ? p11 : lane == 2 ? p21 : p31;
        a0 += bo0;
        a1 += bo1;
        const int myrow = rowbase + lane;
        if (lane < 4 && myrow < MM) {
            const int r2 = coo[myrow] * 2;
            const int c2 = coo[MM + myrow] * 2;
            const long long f0 = (long long)r2 * DD + c2;
            atomicAdd(out + f0, a0);            // (r2, c2)
            atomicAdd(out + f0 + DD + 1, a1);   // (r2+1, c2+1)
        }
    }
#undef HIDDEN
}

extern "C" void kernel_launch(void* const* d_in, const int* in_sizes, int n_in,
                              void* d_out, int out_size, void* d_ws, size_t ws_size,
                              hipStream_t stream) {
    const float* CK   = (const float*)d_in[0];
    const float* Win  = (const float*)d_in[1];
    const float* bin  = (const float*)d_in[2];
    const float* Whid = (const float*)d_in[3];
    const float* bhid = (const float*)d_in[4];
    const float* Wout = (const float*)d_in[5];
    const float* bout = (const float*)d_in[6];
    const int* coo    = (const int*)d_in[7];
    float* out        = (float*)d_out;

    fill_out<<<FILL_BLOCKS, BLK, 0, stream>>>(out);
    mlp_scatter<<<MLP_BLOCKS, BLK, 0, stream>>>(
        CK, Win, bin, Whid, bhid, Wout, bout, coo, out);
}

// Round 10
// 722.883 us; speedup vs baseline: 1.0328x; 1.0193x over previous
//
#include <hip/hip_runtime.h>
#include <stdint.h>

#define NN    6000
#define KNNC  10
#define MM    (NN * 2 * (KNNC + 1))   // 132000
#define DD    (2 * NN)                // 12000
#define LCH   3                       // hidden layers (LC-1)
#define BLK   256

#define MLP_BLOCKS ((MM + BLK - 1) / BLK)   // 516
#define CAP     96                           // bucket capacity (mean 22, 15 sigma)
#define OVF_IDX 8064                         // overflow counter slot inside cnt[]
#define MAX_OVF 4096

// ws layout:
//   [0, 32KB)            : int cnt[8192]   (tile counters + overflow counter) - memset 0
//   [32KB, 32KB+9.22MB)  : float4 bucket[6000*CAP]  {c2_bits, v0, v1, pad}
//   [+9.22MB, +64KB more): int4 ovf[MAX_OVF]        {r, c2, v0_bits, v1_bits}
#define BUCKET_OFF  32768
#define OVF_OFF     (BUCKET_OFF + 6000 * CAP * 16)

// ---------------- kernel 1: MLP + bucket-scatter ---------------------------
// One row per thread (R3 structure - best measured MLP). Instead of random
// atomics into the cold 576MB output (the ~160us invariant: 264k random HBM
// line RMWs), push (c2,v0,v1) into a compact per-row-pair bucket in ws:
// counter atomics hit a 24KB L2-hot region, payload stores are 16B coalesced-ish
// into 9MB (L2-scale). No random HBM transactions.
__global__ __launch_bounds__(BLK) void mlp_bucket(
    const float* __restrict__ CK,    // [MM,3]
    const float* __restrict__ Win,   // [3,64]
    const float* __restrict__ bin,   // [64]
    const float* __restrict__ Whid,  // [3,64,64]
    const float* __restrict__ bhid,  // [3,64]
    const float* __restrict__ Wout,  // [64,4]
    const float* __restrict__ bout,  // [4]
    const int*   __restrict__ coo,   // [2,MM]
    int*    __restrict__ cnt,        // [8192]
    float4* __restrict__ bucket,     // [6000*CAP]
    int4*   __restrict__ ovf)        // [MAX_OVF]
{
    const int m = blockIdx.x * BLK + threadIdx.x;
    if (m >= MM) return;

    const float x0 = CK[m * 3 + 0];
    const float x1 = CK[m * 3 + 1];
    const float x2 = CK[m * 3 + 2];

    // Input layer 3 -> 64; weight/bias reads wave-uniform -> s_load broadcast.
    float h[64];
#pragma unroll
    for (int j = 0; j < 64; j++) {
        float a = bin[j];
        a = fmaf(x0, Win[j],       a);
        a = fmaf(x1, Win[64 + j],  a);
        a = fmaf(x2, Win[128 + j], a);
        h[j] = fmaxf(a, 0.0f);
    }

    // Hidden layers (R3's exact shape: k rolled, j fully unrolled, scalar reads)
#pragma unroll 1
    for (int l = 0; l < LCH; l++) {
        const float* __restrict__ W  = Whid + (l << 12);
        const float* __restrict__ bh = bhid + (l << 6);
        float g[64];
#pragma unroll
        for (int j = 0; j < 64; j++) g[j] = bh[j];
        for (int k = 0; k < 64; k++) {
            const float hk = h[k];
            const float* __restrict__ Wk = W + (k << 6);
#pragma unroll
            for (int j = 0; j < 64; j++) g[j] = fmaf(Wk[j], hk, g[j]);
        }
#pragma unroll
        for (int j = 0; j < 64; j++) h[j] = fmaxf(g[j], 0.0f);
    }

    // Output layer collapsed over mi: vals[:,mj] = C[:,mj] + C[:,mj+2]
    float v0 = bout[0] + bout[2];
    float v1 = bout[1] + bout[3];
#pragma unroll
    for (int k = 0; k < 64; k++) {
        v0 = fmaf(h[k], Wout[k * 4 + 0] + Wout[k * 4 + 2], v0);
        v1 = fmaf(h[k], Wout[k * 4 + 1] + Wout[k * 4 + 3], v1);
    }

    // ---- bucket push ----
    const int r  = coo[m];            // row node, 0..5999 -> tile id
    const int c2 = coo[MM + m] * 2;   // col * MODES
    const int slot = atomicAdd(&cnt[r], 1);
    if (slot < CAP) {
        bucket[r * CAP + slot] = make_float4(__int_as_float(c2), v0, v1, 0.f);
    } else {
        const int o = atomicAdd(&cnt[OVF_IDX], 1);
        if (o < MAX_OVF)
            ovf[o] = make_int4(r, c2, __float_as_int(v0), __float_as_int(v1));
    }
}

// ---------------- kernel 2: fill + patch -----------------------------------
// Block b exclusively owns output rows 2b and 2b+1 (96KB). It streams zeros
// over them, syncs, then applies its bucket entries with atomicAdd to lines
// it JUST wrote -> guaranteed L2-dirty hit on the same XCD, zero random HBM
// RMW. Lines write back once, patches included. Atomics only needed for
// intra-bucket duplicate (r,c) pairs.
__global__ __launch_bounds__(BLK) void fill_patch(
    const int*    __restrict__ cnt,
    const float4* __restrict__ bucket,
    float*        __restrict__ out)
{
    const int b = blockIdx.x;                       // 0..5999
    float* rowbase = out + (long long)b * 2 * DD;   // rows 2b, 2b+1
    float4* dst = (float4*)rowbase;                 // 6000 float4s
    const float4 z = make_float4(0.f, 0.f, 0.f, 0.f);
    for (int i = threadIdx.x; i < 6000; i += BLK) dst[i] = z;
    __syncthreads();

    const int n = min(cnt[b], CAP);
    for (int t = threadIdx.x; t < n; t += BLK) {
        float4 e = bucket[b * CAP + t];
        const int c2 = __float_as_int(e.x);
        atomicAdd(rowbase + c2, e.y);               // (2b,   c2)
        atomicAdd(rowbase + DD + c2 + 1, e.z);      // (2b+1, c2+1)
    }
}

// ---------------- kernel 3: overflow fixup (empty in practice) -------------
__global__ __launch_bounds__(BLK) void ovf_apply(
    const int*  __restrict__ cnt,
    const int4* __restrict__ ovf,
    float*      __restrict__ out)
{
    const int n = min(cnt[OVF_IDX], MAX_OVF);
    const int t = blockIdx.x * BLK + threadIdx.x;
    if (t >= n) return;
    int4 e = ovf[t];
    float* rowbase = out + (long long)e.x * 2 * DD;
    atomicAdd(rowbase + e.y, __int_as_float(e.z));
    atomicAdd(rowbase + DD + e.y + 1, __int_as_float(e.w));
}

extern "C" void kernel_launch(void* const* d_in, const int* in_sizes, int n_in,
                              void* d_out, int out_size, void* d_ws, size_t ws_size,
                              hipStream_t stream) {
    const float* CK   = (const float*)d_in[0];
    const float* Win  = (const float*)d_in[1];
    const float* bin  = (const float*)d_in[2];
    const float* Whid = (const float*)d_in[3];
    const float* bhid = (const float*)d_in[4];
    const float* Wout = (const float*)d_in[5];
    const float* bout = (const float*)d_in[6];
    const int* coo    = (const int*)d_in[7];
    float* out        = (float*)d_out;

    int*    cnt    = (int*)d_ws;
    float4* bucket = (float4*)((char*)d_ws + BUCKET_OFF);
    int4*   ovf    = (int4*)((char*)d_ws + OVF_OFF);

    hipMemsetAsync(cnt, 0, 32768, stream);
    mlp_bucket<<<MLP_BLOCKS, BLK, 0, stream>>>(
        CK, Win, bin, Whid, bhid, Wout, bout, coo, cnt, bucket, ovf);
    fill_patch<<<NN, BLK, 0, stream>>>(cnt, bucket, out);
    ovf_apply<<<(MAX_OVF + BLK - 1) / BLK, BLK, 0, stream>>>(cnt, ovf, out);
}